// Round 5
// baseline (5374.712 us; speedup 1.0000x reference)
//
#include <hip/hip_runtime.h>

using u16 = unsigned short;
using u32 = unsigned int;

typedef short bf16x8 __attribute__((ext_vector_type(8)));
typedef float f32x4  __attribute__((ext_vector_type(4)));

__device__ __forceinline__ float bf2f(u16 u) {
    union { u32 u; float f; } v; v.u = ((u32)u) << 16; return v.f;
}
__device__ __forceinline__ u16 f2bf(float f) {
    union { float f; u32 u; } v; v.f = f;
    u32 r = v.u + 0x7FFFu + ((v.u >> 16) & 1u);   // RNE
    return (u16)(r >> 16);
}
__device__ __forceinline__ float fsig(float x)  { return 1.f / (1.f + __expf(-x)); }
__device__ __forceinline__ float ftanh(float x) { return 1.f - 2.f / (__expf(2.f * x) + 1.f); }

__device__ __forceinline__ uint4 pack8(const u16 h[8]) {
    uint4 u;
    u.x = (u32)h[0] | ((u32)h[1] << 16);
    u.y = (u32)h[2] | ((u32)h[3] << 16);
    u.z = (u32)h[4] | ((u32)h[5] << 16);
    u.w = (u32)h[6] | ((u32)h[7] << 16);
    return u;
}
__device__ __forceinline__ bf16x8 cvt8f(const float* p) {   // fp32x8 -> bf16 frag
    bf16x8 r;
    #pragma unroll
    for (int j = 0; j < 8; ++j) r[j] = (short)f2bf(p[j]);
    return r;
}

// --- device-scope accessors for cross-XCD h-state (kept from round 4) ---
__device__ __forceinline__ u32 aload(const u32* p) {
    return __hip_atomic_load((u32*)p, __ATOMIC_RELAXED, __HIP_MEMORY_SCOPE_AGENT);
}
__device__ __forceinline__ void astore(u32* p, u32 v) {
    __hip_atomic_store(p, v, __ATOMIC_RELAXED, __HIP_MEMORY_SCOPE_AGENT);
}
__device__ __forceinline__ bf16x8 afrag(const u16* base16) { // 16B via 4 coherent dword loads
    union { u32 w[4]; bf16x8 f; } u;
    const u32* p = (const u32*)base16;
    #pragma unroll
    for (int i = 0; i < 4; ++i) u.w[i] = aload(p + i);
    return u.f;
}

// ---------------------------------------------------------------------------
// Dtype sniffer (kept for robustness): flag=1 iff feats is bf16-backed.
// Round-3/4 evidence: fp32 path taken => inputs are fp32.
// ---------------------------------------------------------------------------
__global__ void sniff_dtype(const u16* __restrict__ feats_u16, u32* __restrict__ flag)
{
    __shared__ int cnt;
    const int tid = threadIdx.x;                 // 256 threads
    if (tid == 0) cnt = 0;
    __syncthreads();
    u16 h = feats_u16[2 * tid];
    int e = (h >> 7) & 0xFF;
    int sane = (e >= 64 && e <= 190) ? 1 : 0;
    atomicAdd(&cnt, sane);
    __syncthreads();
    if (tid == 0) flag[0] = (cnt >= 200) ? 1u : 0u;
}

// ---------------------------------------------------------------------------
// Phase 1: x1[t][b][n] = feats[b][t][:] . W_ih1[n][:] + b_ih1[n] + b_hh1[n]
// fp32 path: split-bf16 3-pass (Ah*Bh + Ah*Bl + Al*Bh, error ~2^-17).
// bf16 path: direct, 1 pass. M=32768, N=512, K=1024. 128x128 tile, BK=64.
// ---------------------------------------------------------------------------
template<bool X1F32>
__global__ __launch_bounds__(256) void x1_gemm(
    const void* __restrict__ feats, const void* __restrict__ Wih1,
    const void* __restrict__ bih1, const void* __restrict__ bhh1,
    void* __restrict__ x1p, const u32* __restrict__ dflag)
{
    __shared__ uint4 a_hi[128 * 8];
    __shared__ uint4 a_lo[128 * 8];
    __shared__ uint4 b_hi[128 * 8];
    __shared__ uint4 b_lo[128 * 8];
    const bool isbf16 = (*dflag != 0u);
    const int tid  = threadIdx.x;
    const int lane = tid & 63, wave = tid >> 6;
    const int m0 = blockIdx.x * 128, n0 = blockIdx.y * 128;
    const int wm = (wave >> 1) * 64, wn = (wave & 1) * 64;
    const int lr = lane & 15, lk = lane >> 4;

    f32x4 acc[4][4] = {};

    for (int kt = 0; kt < 1024; kt += 64) {
        __syncthreads();
        #pragma unroll
        for (int it = 0; it < 4; ++it) {
            int idx = tid + it * 256;            // 0..1023
            int row = idx >> 3, c8 = idx & 7;
            int sw  = (row << 3) | (c8 ^ (row & 7));
            size_t offA = (size_t)(m0 + row) * 1024 + kt + c8 * 8;
            size_t offB = (size_t)(n0 + row) * 1024 + kt + c8 * 8;
            if (isbf16) {
                a_hi[sw] = *reinterpret_cast<const uint4*>((const u16*)feats + offA);
                b_hi[sw] = *reinterpret_cast<const uint4*>((const u16*)Wih1 + offB);
            } else {
                {
                    const float* p = (const float*)feats + offA;
                    float4 v0 = *reinterpret_cast<const float4*>(p);
                    float4 v1 = *reinterpret_cast<const float4*>(p + 4);
                    float av[8] = {v0.x, v0.y, v0.z, v0.w, v1.x, v1.y, v1.z, v1.w};
                    u16 h[8], l[8];
                    #pragma unroll
                    for (int j = 0; j < 8; ++j) {
                        h[j] = f2bf(av[j]);
                        l[j] = f2bf(av[j] - bf2f(h[j]));
                    }
                    a_hi[sw] = pack8(h);
                    a_lo[sw] = pack8(l);
                }
                {
                    const float* p = (const float*)Wih1 + offB;
                    float4 v0 = *reinterpret_cast<const float4*>(p);
                    float4 v1 = *reinterpret_cast<const float4*>(p + 4);
                    float bv[8] = {v0.x, v0.y, v0.z, v0.w, v1.x, v1.y, v1.z, v1.w};
                    u16 h[8], l[8];
                    #pragma unroll
                    for (int j = 0; j < 8; ++j) {
                        h[j] = f2bf(bv[j]);
                        l[j] = f2bf(bv[j] - bf2f(h[j]));
                    }
                    b_hi[sw] = pack8(h);
                    b_lo[sw] = pack8(l);
                }
            }
        }
        __syncthreads();
        const int npass = isbf16 ? 1 : 3;
        for (int s = 0; s < npass; ++s) {        // hi*hi, hi*lo, lo*hi
            const uint4* ab = (s == 2) ? a_lo : a_hi;
            const uint4* bb = (s == 1) ? b_lo : b_hi;
            #pragma unroll
            for (int kc = 0; kc < 2; ++kc) {
                bf16x8 af[4], bfr[4];
                #pragma unroll
                for (int i = 0; i < 4; ++i) {
                    int row = wm + i * 16 + lr;
                    af[i] = *reinterpret_cast<const bf16x8*>(&ab[(row << 3) | ((kc * 4 + lk) ^ (row & 7))]);
                }
                #pragma unroll
                for (int j = 0; j < 4; ++j) {
                    int row = wn + j * 16 + lr;
                    bfr[j] = *reinterpret_cast<const bf16x8*>(&bb[(row << 3) | ((kc * 4 + lk) ^ (row & 7))]);
                }
                #pragma unroll
                for (int i = 0; i < 4; ++i)
                    #pragma unroll
                    for (int j = 0; j < 4; ++j)
                        acc[i][j] = __builtin_amdgcn_mfma_f32_16x16x32_bf16(af[i], bfr[j], acc[i][j], 0, 0, 0);
            }
        }
    }
    // Epilogue: D row=(lane>>4)*4+q, col=lane&15. Store permuted to [T,B,512].
    #pragma unroll
    for (int j = 0; j < 4; ++j) {
        int n = n0 + wn + j * 16 + lr;
        float bias = isbf16 ? (bf2f(((const u16*)bih1)[n]) + bf2f(((const u16*)bhh1)[n]))
                            : (((const float*)bih1)[n] + ((const float*)bhh1)[n]);
        #pragma unroll
        for (int i = 0; i < 4; ++i) {
            #pragma unroll
            for (int q = 0; q < 4; ++q) {
                int m = m0 + wm + i * 16 + lk * 4 + q;
                int b = m >> 9, t = m & 511;
                int o = (t * 64 + b) * 512 + n;
                float v = acc[i][j][q] + bias;
                if (X1F32) ((float*)x1p)[o] = v;
                else       ((u16*)x1p)[o]  = f2bf(v);
            }
        }
    }
}

// ---------------------------------------------------------------------------
// Phase 2: persistent pipelined scan. 64 blocks x 256 thr.
// Blocks 0..31: layer1 (round r computes t=r). Blocks 32..63: layer2 (t=r-1).
// OUTPUT IS FP32 (reference computes in fp32; d_out is float*).
// ---------------------------------------------------------------------------
template<bool X1F32>
__global__ __launch_bounds__(256, 1) void lstm_scan(
    const void* __restrict__ Whh1, const void* __restrict__ Wih2,
    const void* __restrict__ Whh2, const void* __restrict__ bih2,
    const void* __restrict__ bhh2, const void* __restrict__ x1p,
    u16* __restrict__ h1buf, u16* __restrict__ h2buf,
    u32* __restrict__ bar, float* __restrict__ out, const u32* __restrict__ dflag)
{
    const bool isbf16 = (*dflag != 0u);
    const int tid  = threadIdx.x;
    const int lane = tid & 63, wave = tid >> 6;
    const int blk  = blockIdx.x;
    const bool is1 = (blk < 32);
    const int sub  = is1 ? blk : blk - 32;
    const int m0   = (sub >> 3) * 16;
    const int jc   = sub & 7;
    const int lr = lane & 15, lk = lane >> 4;
    const int gm = tid >> 4, gc = tid & 15;
    const int hcol = jc * 16 + gc;

    __shared__ float lds_p[4][16][16];

    // persistent weight fragments: B[k][n] = W[n][k]; lane holds n=lr, k=kc*32+lk*8+j
    bf16x8 w1[4], w2a[4], w2b[4];
    {
        const int nrow = wave * 128 + jc * 16 + lr;
        #pragma unroll
        for (int kc = 0; kc < 4; ++kc) {
            const int off = nrow * 128 + kc * 32 + lk * 8;
            if (is1) {
                w1[kc]  = isbf16 ? *reinterpret_cast<const bf16x8*>((const u16*)Whh1 + off)
                                 : cvt8f((const float*)Whh1 + off);
            } else {
                w2a[kc] = isbf16 ? *reinterpret_cast<const bf16x8*>((const u16*)Wih2 + off)
                                 : cvt8f((const float*)Wih2 + off);
                w2b[kc] = isbf16 ? *reinterpret_cast<const bf16x8*>((const u16*)Whh2 + off)
                                 : cvt8f((const float*)Whh2 + off);
            }
        }
    }
    float b2v[4] = {0.f, 0.f, 0.f, 0.f};
    if (!is1) {
        #pragma unroll
        for (int g = 0; g < 4; ++g) {
            int n = g * 128 + hcol;
            b2v[g] = isbf16 ? (bf2f(((const u16*)bih2)[n]) + bf2f(((const u16*)bhh2)[n]))
                            : (((const float*)bih2)[n] + ((const float*)bhh2)[n]);
        }
    }

    float c_reg = 0.f;        // fp32 cell state, in-register all 512 steps
    float xn[4];              // prefetched x1(t+1)
    if (is1) {
        #pragma unroll
        for (int g = 0; g < 4; ++g) {
            int o = (m0 + gm) * 512 + g * 128 + hcol;   // t=0
            xn[g] = X1F32 ? ((const float*)x1p)[o] : bf2f(((const u16*)x1p)[o]);
        }
    }

    for (int r = 0; r <= 512; ++r) {
        // ---- grid barrier (monotonic counter, release-add / acquire-spin) ----
        __syncthreads();
        if (tid == 0) {
            __hip_atomic_fetch_add(bar, 1u, __ATOMIC_RELEASE, __HIP_MEMORY_SCOPE_AGENT);
            const u32 target = 64u * (u32)(r + 1);
            while (__hip_atomic_load(bar, __ATOMIC_ACQUIRE, __HIP_MEMORY_SCOPE_AGENT) < target)
                __builtin_amdgcn_s_sleep(1);
        }
        __syncthreads();
        __builtin_amdgcn_fence(__ATOMIC_ACQUIRE, "agent");

        const u16* hin1  = h1buf + (r & 1) * 8192;
        const u16* hin2  = h2buf + (r & 1) * 8192;
        u16*       hout1 = h1buf + ((r + 1) & 1) * 8192;
        u16*       hout2 = h2buf + ((r + 1) & 1) * 8192;

        if (is1) {
            if (r < 512) {
                float xc[4];
                #pragma unroll
                for (int g = 0; g < 4; ++g) xc[g] = xn[g];

                bf16x8 a[4];
                #pragma unroll
                for (int kc = 0; kc < 4; ++kc)
                    a[kc] = afrag(hin1 + (m0 + lr) * 128 + kc * 32 + lk * 8);
                if (r + 1 < 512) {   // next-round x1 prefetch, off critical path
                    #pragma unroll
                    for (int g = 0; g < 4; ++g) {
                        int o = ((r + 1) * 64 + m0 + gm) * 512 + g * 128 + hcol;
                        xn[g] = X1F32 ? ((const float*)x1p)[o] : bf2f(((const u16*)x1p)[o]);
                    }
                }
                f32x4 acc = {0.f, 0.f, 0.f, 0.f};
                #pragma unroll
                for (int kc = 0; kc < 4; ++kc)
                    acc = __builtin_amdgcn_mfma_f32_16x16x32_bf16(a[kc], w1[kc], acc, 0, 0, 0);

                #pragma unroll
                for (int q = 0; q < 4; ++q) lds_p[wave][lk * 4 + q][lr] = acc[q];
                __syncthreads();

                float pi = lds_p[0][gm][gc] + xc[0];
                float pf = lds_p[1][gm][gc] + xc[1];
                float pg = lds_p[2][gm][gc] + xc[2];
                float po = lds_p[3][gm][gc] + xc[3];
                float ig = fsig(pi), fg = fsig(pf), gg = ftanh(pg), og = fsig(po);
                c_reg = fg * c_reg + ig * gg;
                float h = og * ftanh(c_reg);
                u32 mine = f2bf(h);
                u32 part = (u32)__shfl_xor((int)mine, 1, 64);
                if (!(gc & 1)) {
                    u32 packed = mine | (part << 16);
                    astore((u32*)hout1 + ((m0 + gm) * 128 + hcol) / 2, packed);
                }
            }
        } else {
            if (r >= 1) {
                const int t2 = r - 1;
                bf16x8 a1[4], a2[4];
                #pragma unroll
                for (int kc = 0; kc < 4; ++kc)
                    a1[kc] = afrag(hin1 + (m0 + lr) * 128 + kc * 32 + lk * 8);
                #pragma unroll
                for (int kc = 0; kc < 4; ++kc)
                    a2[kc] = afrag(hin2 + (m0 + lr) * 128 + kc * 32 + lk * 8);

                f32x4 acc = {0.f, 0.f, 0.f, 0.f};
                #pragma unroll
                for (int kc = 0; kc < 4; ++kc)
                    acc = __builtin_amdgcn_mfma_f32_16x16x32_bf16(a1[kc], w2a[kc], acc, 0, 0, 0);
                #pragma unroll
                for (int kc = 0; kc < 4; ++kc)
                    acc = __builtin_amdgcn_mfma_f32_16x16x32_bf16(a2[kc], w2b[kc], acc, 0, 0, 0);

                #pragma unroll
                for (int q = 0; q < 4; ++q) lds_p[wave][lk * 4 + q][lr] = acc[q];
                __syncthreads();

                float pi = lds_p[0][gm][gc] + b2v[0];
                float pf = lds_p[1][gm][gc] + b2v[1];
                float pg = lds_p[2][gm][gc] + b2v[2];
                float po = lds_p[3][gm][gc] + b2v[3];
                float ig = fsig(pi), fg = fsig(pf), gg = ftanh(pg), og = fsig(po);
                c_reg = fg * c_reg + ig * gg;
                float h = og * ftanh(c_reg);
                u32 mine = f2bf(h);
                u32 part = (u32)__shfl_xor((int)mine, 1, 64);
                if (!(gc & 1)) {
                    u32 packed = mine | (part << 16);
                    astore((u32*)hout2 + ((m0 + gm) * 128 + hcol) / 2, packed);
                }
                // d_out is FP32 [B,T,O]; write full-precision h
                out[((m0 + gm) * 512 + t2) * 128 + hcol] = h;
            }
        }
    }
}

// ---------------------------------------------------------------------------
extern "C" void kernel_launch(void* const* d_in, const int* in_sizes, int n_in,
                              void* d_out, int out_size, void* d_ws, size_t ws_size,
                              hipStream_t stream)
{
    const void* feats = d_in[0];
    const void* Wih1  = d_in[1];
    const void* Whh1  = d_in[2];
    const void* bih1  = d_in[3];
    const void* bhh1  = d_in[4];
    const void* Wih2  = d_in[5];
    const void* Whh2  = d_in[6];
    const void* bih2  = d_in[7];
    const void* bhh2  = d_in[8];
    float* out = (float*)d_out;

    const size_t x1f32 = (size_t)32768 * 512 * 4;   // 64 MB
    const size_t x1bf  = (size_t)32768 * 512 * 2;   // 32 MB
    const size_t state = 32768 /*h1*/ + 32768 /*h2*/ + 64 /*bar*/ + 64 /*flag*/;
    const bool f32ok = ws_size >= x1f32 + state;

    char* ws = (char*)d_ws;
    const size_t x1_bytes = f32ok ? x1f32 : x1bf;
    void* x1p   = ws;
    u16* h1buf  = (u16*)(ws + x1_bytes);
    u16* h2buf  = h1buf + 2 * 8192;
    u32* bar    = (u32*)(ws + x1_bytes + 65536);
    u32* dflag  = (u32*)(ws + x1_bytes + 65600);

    // zero h ping-pong buffers + barrier counter (+flag; sniffer rewrites it)
    hipMemsetAsync(ws + x1_bytes, 0, state, stream);
    sniff_dtype<<<1, 256, 0, stream>>>((const u16*)feats, dflag);

    if (f32ok) {
        x1_gemm<true><<<dim3(256, 4), 256, 0, stream>>>(feats, Wih1, bih1, bhh1, x1p, dflag);
        lstm_scan<true><<<64, 256, 0, stream>>>(Whh1, Wih2, Whh2, bih2, bhh2,
                                                x1p, h1buf, h2buf, bar, out, dflag);
    } else {
        x1_gemm<false><<<dim3(256, 4), 256, 0, stream>>>(feats, Wih1, bih1, bhh1, x1p, dflag);
        lstm_scan<false><<<64, 256, 0, stream>>>(Whh1, Wih2, Whh2, bih2, bhh2,
                                                 x1p, h1buf, h2buf, bar, out, dflag);
    }
    (void)in_sizes; (void)n_in; (void)out_size;
}

// Round 6
// 3790.491 us; speedup vs baseline: 1.4179x; 1.4179x over previous
//
#include <hip/hip_runtime.h>

using u16 = unsigned short;
using u32 = unsigned int;

typedef short bf16x8 __attribute__((ext_vector_type(8)));
typedef float f32x4  __attribute__((ext_vector_type(4)));

__device__ __forceinline__ float bf2f(u16 u) {
    union { u32 u; float f; } v; v.u = ((u32)u) << 16; return v.f;
}
__device__ __forceinline__ u16 f2bf(float f) {
    union { float f; u32 u; } v; v.f = f;
    u32 r = v.u + 0x7FFFu + ((v.u >> 16) & 1u);   // RNE
    return (u16)(r >> 16);
}
__device__ __forceinline__ float fsig(float x)  { return 1.f / (1.f + __expf(-x)); }
__device__ __forceinline__ float ftanh(float x) { return 1.f - 2.f / (__expf(2.f * x) + 1.f); }

__device__ __forceinline__ uint4 pack8(const u16 h[8]) {
    uint4 u;
    u.x = (u32)h[0] | ((u32)h[1] << 16);
    u.y = (u32)h[2] | ((u32)h[3] << 16);
    u.z = (u32)h[4] | ((u32)h[5] << 16);
    u.w = (u32)h[6] | ((u32)h[7] << 16);
    return u;
}
__device__ __forceinline__ bf16x8 cvt8f(const float* p) {   // fp32x8 -> bf16 frag
    bf16x8 r;
    #pragma unroll
    for (int j = 0; j < 8; ++j) r[j] = (short)f2bf(p[j]);
    return r;
}

// --- agent-scope (IC coherence point) accessors for cross-XCD h-state.
// RELAXED only: atomics bypass the non-coherent L1/L2, so visibility comes
// from the access itself; ordering comes from __syncthreads' vmcnt(0) drain.
// NO release/acquire anywhere in the hot loop — those lower to buffer_wbl2 /
// buffer_inv (cache-wide ops, ~us each) and were the 10 us/round cost (r5).
__device__ __forceinline__ u32 aload(const u32* p) {
    return __hip_atomic_load((u32*)p, __ATOMIC_RELAXED, __HIP_MEMORY_SCOPE_AGENT);
}
__device__ __forceinline__ void astore(u32* p, u32 v) {
    __hip_atomic_store(p, v, __ATOMIC_RELAXED, __HIP_MEMORY_SCOPE_AGENT);
}
__device__ __forceinline__ bf16x8 afrag(const u16* base16) { // 16B via 4 coherent dword loads
    union { u32 w[4]; bf16x8 f; } u;
    const u32* p = (const u32*)base16;
    #pragma unroll
    for (int i = 0; i < 4; ++i) u.w[i] = aload(p + i);
    return u.f;
}

// ---------------------------------------------------------------------------
// Dtype sniffer (kept for robustness): flag=1 iff feats is bf16-backed.
// Rounds 3-5 evidence: inputs are fp32; fp32 path is the live one.
// ---------------------------------------------------------------------------
__global__ void sniff_dtype(const u16* __restrict__ feats_u16, u32* __restrict__ flag)
{
    __shared__ int cnt;
    const int tid = threadIdx.x;                 // 256 threads
    if (tid == 0) cnt = 0;
    __syncthreads();
    u16 h = feats_u16[2 * tid];
    int e = (h >> 7) & 0xFF;
    int sane = (e >= 64 && e <= 190) ? 1 : 0;
    atomicAdd(&cnt, sane);
    __syncthreads();
    if (tid == 0) flag[0] = (cnt >= 200) ? 1u : 0u;
}

// ---------------------------------------------------------------------------
// Phase 1: x1[t][b][n] = feats[b][t][:] . W_ih1[n][:] + b_ih1[n] + b_hh1[n]
// fp32 path: split-bf16 3-pass (Ah*Bh + Ah*Bl + Al*Bh, error ~2^-17).
// bf16 path: direct, 1 pass. M=32768, N=512, K=1024. 128x128 tile, BK=64.
// ---------------------------------------------------------------------------
template<bool X1F32>
__global__ __launch_bounds__(256) void x1_gemm(
    const void* __restrict__ feats, const void* __restrict__ Wih1,
    const void* __restrict__ bih1, const void* __restrict__ bhh1,
    void* __restrict__ x1p, const u32* __restrict__ dflag)
{
    __shared__ uint4 a_hi[128 * 8];
    __shared__ uint4 a_lo[128 * 8];
    __shared__ uint4 b_hi[128 * 8];
    __shared__ uint4 b_lo[128 * 8];
    const bool isbf16 = (*dflag != 0u);
    const int tid  = threadIdx.x;
    const int lane = tid & 63, wave = tid >> 6;
    const int m0 = blockIdx.x * 128, n0 = blockIdx.y * 128;
    const int wm = (wave >> 1) * 64, wn = (wave & 1) * 64;
    const int lr = lane & 15, lk = lane >> 4;

    f32x4 acc[4][4] = {};

    for (int kt = 0; kt < 1024; kt += 64) {
        __syncthreads();
        #pragma unroll
        for (int it = 0; it < 4; ++it) {
            int idx = tid + it * 256;            // 0..1023
            int row = idx >> 3, c8 = idx & 7;
            int sw  = (row << 3) | (c8 ^ (row & 7));
            size_t offA = (size_t)(m0 + row) * 1024 + kt + c8 * 8;
            size_t offB = (size_t)(n0 + row) * 1024 + kt + c8 * 8;
            if (isbf16) {
                a_hi[sw] = *reinterpret_cast<const uint4*>((const u16*)feats + offA);
                b_hi[sw] = *reinterpret_cast<const uint4*>((const u16*)Wih1 + offB);
            } else {
                {
                    const float* p = (const float*)feats + offA;
                    float4 v0 = *reinterpret_cast<const float4*>(p);
                    float4 v1 = *reinterpret_cast<const float4*>(p + 4);
                    float av[8] = {v0.x, v0.y, v0.z, v0.w, v1.x, v1.y, v1.z, v1.w};
                    u16 h[8], l[8];
                    #pragma unroll
                    for (int j = 0; j < 8; ++j) {
                        h[j] = f2bf(av[j]);
                        l[j] = f2bf(av[j] - bf2f(h[j]));
                    }
                    a_hi[sw] = pack8(h);
                    a_lo[sw] = pack8(l);
                }
                {
                    const float* p = (const float*)Wih1 + offB;
                    float4 v0 = *reinterpret_cast<const float4*>(p);
                    float4 v1 = *reinterpret_cast<const float4*>(p + 4);
                    float bv[8] = {v0.x, v0.y, v0.z, v0.w, v1.x, v1.y, v1.z, v1.w};
                    u16 h[8], l[8];
                    #pragma unroll
                    for (int j = 0; j < 8; ++j) {
                        h[j] = f2bf(bv[j]);
                        l[j] = f2bf(bv[j] - bf2f(h[j]));
                    }
                    b_hi[sw] = pack8(h);
                    b_lo[sw] = pack8(l);
                }
            }
        }
        __syncthreads();
        const int npass = isbf16 ? 1 : 3;
        for (int s = 0; s < npass; ++s) {        // hi*hi, hi*lo, lo*hi
            const uint4* ab = (s == 2) ? a_lo : a_hi;
            const uint4* bb = (s == 1) ? b_lo : b_hi;
            #pragma unroll
            for (int kc = 0; kc < 2; ++kc) {
                bf16x8 af[4], bfr[4];
                #pragma unroll
                for (int i = 0; i < 4; ++i) {
                    int row = wm + i * 16 + lr;
                    af[i] = *reinterpret_cast<const bf16x8*>(&ab[(row << 3) | ((kc * 4 + lk) ^ (row & 7))]);
                }
                #pragma unroll
                for (int j = 0; j < 4; ++j) {
                    int row = wn + j * 16 + lr;
                    bfr[j] = *reinterpret_cast<const bf16x8*>(&bb[(row << 3) | ((kc * 4 + lk) ^ (row & 7))]);
                }
                #pragma unroll
                for (int i = 0; i < 4; ++i)
                    #pragma unroll
                    for (int j = 0; j < 4; ++j)
                        acc[i][j] = __builtin_amdgcn_mfma_f32_16x16x32_bf16(af[i], bfr[j], acc[i][j], 0, 0, 0);
            }
        }
    }
    // Epilogue: D row=(lane>>4)*4+q, col=lane&15. Store permuted to [T,B,512].
    #pragma unroll
    for (int j = 0; j < 4; ++j) {
        int n = n0 + wn + j * 16 + lr;
        float bias = isbf16 ? (bf2f(((const u16*)bih1)[n]) + bf2f(((const u16*)bhh1)[n]))
                            : (((const float*)bih1)[n] + ((const float*)bhh1)[n]);
        #pragma unroll
        for (int i = 0; i < 4; ++i) {
            #pragma unroll
            for (int q = 0; q < 4; ++q) {
                int m = m0 + wm + i * 16 + lk * 4 + q;
                int b = m >> 9, t = m & 511;
                int o = (t * 64 + b) * 512 + n;
                float v = acc[i][j][q] + bias;
                if (X1F32) ((float*)x1p)[o] = v;
                else       ((u16*)x1p)[o]  = f2bf(v);
            }
        }
    }
}

// ---------------------------------------------------------------------------
// Phase 2: persistent pipelined scan. 64 blocks x 256 thr.
// Blocks 0..31: layer1 (round r computes t=r). Blocks 32..63: layer2 (t=r-1).
// Barrier: ALL-RELAXED monotonic counter. Producer ordering = __syncthreads'
// vmcnt(0) drain (h atomic stores complete at IC before tid0's add issues).
// Consumer freshness = data loads are themselves agent-scope atomics.
// ---------------------------------------------------------------------------
template<bool X1F32>
__global__ __launch_bounds__(256, 1) void lstm_scan(
    const void* __restrict__ Whh1, const void* __restrict__ Wih2,
    const void* __restrict__ Whh2, const void* __restrict__ bih2,
    const void* __restrict__ bhh2, const void* __restrict__ x1p,
    u16* __restrict__ h1buf, u16* __restrict__ h2buf,
    u32* __restrict__ bar, float* __restrict__ out, const u32* __restrict__ dflag)
{
    const bool isbf16 = (*dflag != 0u);
    const int tid  = threadIdx.x;
    const int lane = tid & 63, wave = tid >> 6;
    const int blk  = blockIdx.x;
    const bool is1 = (blk < 32);
    const int sub  = is1 ? blk : blk - 32;
    const int m0   = (sub >> 3) * 16;
    const int jc   = sub & 7;
    const int lr = lane & 15, lk = lane >> 4;
    const int gm = tid >> 4, gc = tid & 15;
    const int hcol = jc * 16 + gc;

    __shared__ float lds_p[4][16][16];

    // persistent weight fragments: B[k][n] = W[n][k]; lane holds n=lr, k=kc*32+lk*8+j
    bf16x8 w1[4], w2a[4], w2b[4];
    {
        const int nrow = wave * 128 + jc * 16 + lr;
        #pragma unroll
        for (int kc = 0; kc < 4; ++kc) {
            const int off = nrow * 128 + kc * 32 + lk * 8;
            if (is1) {
                w1[kc]  = isbf16 ? *reinterpret_cast<const bf16x8*>((const u16*)Whh1 + off)
                                 : cvt8f((const float*)Whh1 + off);
            } else {
                w2a[kc] = isbf16 ? *reinterpret_cast<const bf16x8*>((const u16*)Wih2 + off)
                                 : cvt8f((const float*)Wih2 + off);
                w2b[kc] = isbf16 ? *reinterpret_cast<const bf16x8*>((const u16*)Whh2 + off)
                                 : cvt8f((const float*)Whh2 + off);
            }
        }
    }
    float b2v[4] = {0.f, 0.f, 0.f, 0.f};
    if (!is1) {
        #pragma unroll
        for (int g = 0; g < 4; ++g) {
            int n = g * 128 + hcol;
            b2v[g] = isbf16 ? (bf2f(((const u16*)bih2)[n]) + bf2f(((const u16*)bhh2)[n]))
                            : (((const float*)bih2)[n] + ((const float*)bhh2)[n]);
        }
    }

    float c_reg = 0.f;        // fp32 cell state, in-register all 512 steps
    float xn[4];              // prefetched x1(t+1)
    if (is1) {
        #pragma unroll
        for (int g = 0; g < 4; ++g) {
            int o = (m0 + gm) * 512 + g * 128 + hcol;   // t=0
            xn[g] = X1F32 ? ((const float*)x1p)[o] : bf2f(((const u16*)x1p)[o]);
        }
    }

    for (int r = 0; r <= 512; ++r) {
        // ---- grid barrier: all-relaxed monotonic counter ----
        __syncthreads();   // drains vmcnt(0): this block's h atomic-stores are complete at IC
        if (tid == 0) {
            __hip_atomic_fetch_add(bar, 1u, __ATOMIC_RELAXED, __HIP_MEMORY_SCOPE_AGENT);
            const u32 target = 64u * (u32)(r + 1);
            while (__hip_atomic_load(bar, __ATOMIC_RELAXED, __HIP_MEMORY_SCOPE_AGENT) < target)
                __builtin_amdgcn_s_sleep(1);
        }
        __syncthreads();
        // no acquire fence: h loads below are agent-scope atomics (IC-coherent)

        const u16* hin1  = h1buf + (r & 1) * 8192;
        const u16* hin2  = h2buf + (r & 1) * 8192;
        u16*       hout1 = h1buf + ((r + 1) & 1) * 8192;
        u16*       hout2 = h2buf + ((r + 1) & 1) * 8192;

        if (is1) {
            if (r < 512) {
                float xc[4];
                #pragma unroll
                for (int g = 0; g < 4; ++g) xc[g] = xn[g];

                bf16x8 a[4];
                #pragma unroll
                for (int kc = 0; kc < 4; ++kc)
                    a[kc] = afrag(hin1 + (m0 + lr) * 128 + kc * 32 + lk * 8);
                if (r + 1 < 512) {   // next-round x1 prefetch, off critical path
                    #pragma unroll
                    for (int g = 0; g < 4; ++g) {
                        int o = ((r + 1) * 64 + m0 + gm) * 512 + g * 128 + hcol;
                        xn[g] = X1F32 ? ((const float*)x1p)[o] : bf2f(((const u16*)x1p)[o]);
                    }
                }
                f32x4 acc = {0.f, 0.f, 0.f, 0.f};
                #pragma unroll
                for (int kc = 0; kc < 4; ++kc)
                    acc = __builtin_amdgcn_mfma_f32_16x16x32_bf16(a[kc], w1[kc], acc, 0, 0, 0);

                #pragma unroll
                for (int q = 0; q < 4; ++q) lds_p[wave][lk * 4 + q][lr] = acc[q];
                __syncthreads();

                float pi = lds_p[0][gm][gc] + xc[0];
                float pf = lds_p[1][gm][gc] + xc[1];
                float pg = lds_p[2][gm][gc] + xc[2];
                float po = lds_p[3][gm][gc] + xc[3];
                float ig = fsig(pi), fg = fsig(pf), gg = ftanh(pg), og = fsig(po);
                c_reg = fg * c_reg + ig * gg;
                float h = og * ftanh(c_reg);
                u32 mine = f2bf(h);
                u32 part = (u32)__shfl_xor((int)mine, 1, 64);
                if (!(gc & 1)) {
                    u32 packed = mine | (part << 16);
                    astore((u32*)hout1 + ((m0 + gm) * 128 + hcol) / 2, packed);
                }
            }
        } else {
            if (r >= 1) {
                const int t2 = r - 1;
                bf16x8 a1[4], a2[4];
                #pragma unroll
                for (int kc = 0; kc < 4; ++kc)
                    a1[kc] = afrag(hin1 + (m0 + lr) * 128 + kc * 32 + lk * 8);
                #pragma unroll
                for (int kc = 0; kc < 4; ++kc)
                    a2[kc] = afrag(hin2 + (m0 + lr) * 128 + kc * 32 + lk * 8);

                f32x4 acc = {0.f, 0.f, 0.f, 0.f};
                #pragma unroll
                for (int kc = 0; kc < 4; ++kc)
                    acc = __builtin_amdgcn_mfma_f32_16x16x32_bf16(a1[kc], w2a[kc], acc, 0, 0, 0);
                #pragma unroll
                for (int kc = 0; kc < 4; ++kc)
                    acc = __builtin_amdgcn_mfma_f32_16x16x32_bf16(a2[kc], w2b[kc], acc, 0, 0, 0);

                #pragma unroll
                for (int q = 0; q < 4; ++q) lds_p[wave][lk * 4 + q][lr] = acc[q];
                __syncthreads();

                float pi = lds_p[0][gm][gc] + b2v[0];
                float pf = lds_p[1][gm][gc] + b2v[1];
                float pg = lds_p[2][gm][gc] + b2v[2];
                float po = lds_p[3][gm][gc] + b2v[3];
                float ig = fsig(pi), fg = fsig(pf), gg = ftanh(pg), og = fsig(po);
                c_reg = fg * c_reg + ig * gg;
                float h = og * ftanh(c_reg);
                u32 mine = f2bf(h);
                u32 part = (u32)__shfl_xor((int)mine, 1, 64);
                if (!(gc & 1)) {
                    u32 packed = mine | (part << 16);
                    astore((u32*)hout2 + ((m0 + gm) * 128 + hcol) / 2, packed);
                }
                // d_out is FP32 [B,T,O]; write full-precision h
                out[((m0 + gm) * 512 + t2) * 128 + hcol] = h;
            }
        }
    }
}

// ---------------------------------------------------------------------------
extern "C" void kernel_launch(void* const* d_in, const int* in_sizes, int n_in,
                              void* d_out, int out_size, void* d_ws, size_t ws_size,
                              hipStream_t stream)
{
    const void* feats = d_in[0];
    const void* Wih1  = d_in[1];
    const void* Whh1  = d_in[2];
    const void* bih1  = d_in[3];
    const void* bhh1  = d_in[4];
    const void* Wih2  = d_in[5];
    const void* Whh2  = d_in[6];
    const void* bih2  = d_in[7];
    const void* bhh2  = d_in[8];
    float* out = (float*)d_out;

    const size_t x1f32 = (size_t)32768 * 512 * 4;   // 64 MB
    const size_t x1bf  = (size_t)32768 * 512 * 2;   // 32 MB
    const size_t state = 32768 /*h1*/ + 32768 /*h2*/ + 64 /*bar*/ + 64 /*flag*/;
    const bool f32ok = ws_size >= x1f32 + state;

    char* ws = (char*)d_ws;
    const size_t x1_bytes = f32ok ? x1f32 : x1bf;
    void* x1p   = ws;
    u16* h1buf  = (u16*)(ws + x1_bytes);
    u16* h2buf  = h1buf + 2 * 8192;
    u32* bar    = (u32*)(ws + x1_bytes + 65536);
    u32* dflag  = (u32*)(ws + x1_bytes + 65600);

    // zero h ping-pong buffers + barrier counter (+flag; sniffer rewrites it)
    hipMemsetAsync(ws + x1_bytes, 0, state, stream);
    sniff_dtype<<<1, 256, 0, stream>>>((const u16*)feats, dflag);

    if (f32ok) {
        x1_gemm<true><<<dim3(256, 4), 256, 0, stream>>>(feats, Wih1, bih1, bhh1, x1p, dflag);
        lstm_scan<true><<<64, 256, 0, stream>>>(Whh1, Wih2, Whh2, bih2, bhh2,
                                                x1p, h1buf, h2buf, bar, out, dflag);
    } else {
        x1_gemm<false><<<dim3(256, 4), 256, 0, stream>>>(feats, Wih1, bih1, bhh1, x1p, dflag);
        lstm_scan<false><<<64, 256, 0, stream>>>(Whh1, Wih2, Whh2, bih2, bhh2,
                                                 x1p, h1buf, h2buf, bar, out, dflag);
    }
    (void)in_sizes; (void)n_in; (void)out_size;
}